// Round 7
// baseline (94.946 us; speedup 1.0000x reference)
//
#include <hip/hip_runtime.h>

// Problem constants (pinned by the reference)
#define UNITS     49152
#define INPUT_DIM 15
#define BATCH     2048

constexpr int TPB            = 256;
constexpr int U_PER_THREAD   = 4;                          // float4 along U
constexpr int U_PER_BLOCK    = TPB * U_PER_THREAD;         // 1024
constexpr int BLOCKS_PER_ROW = UNITS / U_PER_BLOCK;        // 48
constexpr int ROWS_PER_ITER  = 32;                         // rows swept per global iteration
constexpr int NBLOCKS        = BLOCKS_PER_ROW * ROWS_PER_ITER;  // 1536
constexpr int NITER          = BATCH / ROWS_PER_ITER;      // 64

typedef float f32x4 __attribute__((ext_vector_type(4)));

// One-time premask: mw[i][u] = w[i][u] * mask[u][i] (coalesced; ~2 us)
__global__ __launch_bounds__(TPB) void premask_kernel(
    const float* __restrict__ w,     // [INPUT_DIM, UNITS]
    const float* __restrict__ mask,  // [UNITS, INPUT_DIM]
    float* __restrict__ mw)          // [INPUT_DIM, UNITS]
{
    const int u = blockIdx.x * TPB + threadIdx.x;
    float m[INPUT_DIM];
#pragma unroll
    for (int i = 0; i < INPUT_DIM; ++i) m[i] = mask[(size_t)u * INPUT_DIM + i];
#pragma unroll
    for (int i = 0; i < INPUT_DIM; ++i)
        mw[(size_t)i * UNITS + u] = w[(size_t)i * UNITS + u] * m[i];
}

// Lockstep row sweep: at iteration k the ENTIRE grid writes rows
// [32k, 32k+32) — one contiguous 6 MB window sweeping through out[].
// Block b: fixed col-slice (b%48)*1024, row phase b/48.
template <bool PREMASKED>
__global__ __launch_bounds__(TPB) void striatum_kernel(
    const float* __restrict__ x,     // [BATCH, INPUT_DIM]
    const float* __restrict__ w,     // [INPUT_DIM, UNITS] (premasked if PREMASKED)
    const float* __restrict__ bias,  // [UNITS]
    const float* __restrict__ mask,  // [UNITS, INPUT_DIM] (unused if PREMASKED)
    float* __restrict__ out)         // [BATCH, UNITS]
{
    const int b        = blockIdx.x;
    const int row_base = b / BLOCKS_PER_ROW;   // 0..31 — phase within the window
    const int colblk   = b % BLOCKS_PER_ROW;   // 0..47 — fixed column slice
    const int u0       = colblk * U_PER_BLOCK + threadIdx.x * U_PER_THREAD;

    // This thread's 4 fixed weight columns in registers (coalesced float4 loads).
    f32x4 mw[INPUT_DIM];
#pragma unroll
    for (int i = 0; i < INPUT_DIM; ++i) {
        f32x4 wv = *reinterpret_cast<const f32x4*>(&w[(size_t)i * UNITS + u0]);
        if constexpr (!PREMASKED) {
            wv.x *= mask[(size_t)(u0 + 0) * INPUT_DIM + i];
            wv.y *= mask[(size_t)(u0 + 1) * INPUT_DIM + i];
            wv.z *= mask[(size_t)(u0 + 2) * INPUT_DIM + i];
            wv.w *= mask[(size_t)(u0 + 3) * INPUT_DIM + i];
        }
        mw[i] = wv;
    }
    const f32x4 bv = *reinterpret_cast<const f32x4*>(&bias[u0]);

    // Sweep rows in global lockstep; x row is wave-uniform -> scalar loads.
    for (int k = 0; k < NITER; ++k) {
        const int row = k * ROWS_PER_ITER + row_base;
        const float* __restrict__ xr = x + (size_t)row * INPUT_DIM;  // uniform addr
        f32x4 acc = bv;
#pragma unroll
        for (int i = 0; i < INPUT_DIM; ++i) {
            const float xv = xr[i];
            acc.x = fmaf(xv, mw[i].x, acc.x);
            acc.y = fmaf(xv, mw[i].y, acc.y);
            acc.z = fmaf(xv, mw[i].z, acc.z);
            acc.w = fmaf(xv, mw[i].w, acc.w);
        }
        __builtin_nontemporal_store(acc,
            reinterpret_cast<f32x4*>(&out[(size_t)row * UNITS + u0]));
    }
}

extern "C" void kernel_launch(void* const* d_in, const int* in_sizes, int n_in,
                              void* d_out, int out_size, void* d_ws, size_t ws_size,
                              hipStream_t stream) {
    const float* x    = (const float*)d_in[0];  // inputs [2048, 15]
    const float* w    = (const float*)d_in[1];  // w      [15, 49152]
    const float* b    = (const float*)d_in[2];  // b      [49152]
    const float* mask = (const float*)d_in[3];  // mask   [49152, 15]
    float* out        = (float*)d_out;          // [2048, 49152]

    const size_t mw_bytes = (size_t)INPUT_DIM * UNITS * sizeof(float);  // 2.95 MB

    if (ws_size >= mw_bytes) {
        float* mw = (float*)d_ws;
        premask_kernel<<<UNITS / TPB, TPB, 0, stream>>>(w, mask, mw);
        striatum_kernel<true><<<NBLOCKS, TPB, 0, stream>>>(x, mw, b, mask, out);
    } else {
        striatum_kernel<false><<<NBLOCKS, TPB, 0, stream>>>(x, w, b, mask, out);
    }
}

// Round 8
// 94.398 us; speedup vs baseline: 1.0058x; 1.0058x over previous
//
#include <hip/hip_runtime.h>

// Problem constants (pinned by the reference)
#define UNITS     49152
#define INPUT_DIM 15
#define BATCH     2048

constexpr int TPB            = 384;                    // 6 waves/block
constexpr int U_PER_THREAD   = 4;                      // float4 along U
constexpr int U_PER_BLOCK    = TPB * U_PER_THREAD;     // 1536
constexpr int COL_BLOCKS     = UNITS / U_PER_BLOCK;    // 32
constexpr int ROW_GROUPS     = 8;
constexpr int ROWS_PER_BLOCK = BATCH / ROW_GROUPS;     // 256
constexpr int XS_STRIDE      = 16;                     // padded row stride
constexpr int R_UNROLL       = 4;                      // rows in flight per wave

typedef float f32x4 __attribute__((ext_vector_type(4)));

// One-time premask: mw[i][u] = w[i][u] * mask[u][i] (coalesced; ~2 us)
__global__ __launch_bounds__(256) void premask_kernel(
    const float* __restrict__ w,     // [INPUT_DIM, UNITS]
    const float* __restrict__ mask,  // [UNITS, INPUT_DIM]
    float* __restrict__ mw)          // [INPUT_DIM, UNITS]
{
    const int u = blockIdx.x * 256 + threadIdx.x;
    float m[INPUT_DIM];
#pragma unroll
    for (int i = 0; i < INPUT_DIM; ++i) m[i] = mask[(size_t)u * INPUT_DIM + i];
#pragma unroll
    for (int i = 0; i < INPUT_DIM; ++i)
        mw[(size_t)i * UNITS + u] = w[(size_t)i * UNITS + u] * m[i];
}

// Fill-mimicking low-occupancy writer: exactly 1 block per CU (32x8 grid),
// 6 waves/CU (~19% occupancy) -> ~1536 concurrent store streams instead of
// ~6144. Weights fixed in registers; 4 rows in flight per wave.
template <bool PREMASKED>
__global__ __launch_bounds__(TPB) void striatum_kernel(
    const float* __restrict__ x,     // [BATCH, INPUT_DIM]
    const float* __restrict__ w,     // [INPUT_DIM, UNITS] (premasked if PREMASKED)
    const float* __restrict__ bias,  // [UNITS]
    const float* __restrict__ mask,  // [UNITS, INPUT_DIM] (unused if PREMASKED)
    float* __restrict__ out)         // [BATCH, UNITS]
{
    __shared__ __align__(16) float xs[ROWS_PER_BLOCK * XS_STRIDE];  // 16 KB

    const int u0   = blockIdx.x * U_PER_BLOCK + threadIdx.x * U_PER_THREAD;
    const int row0 = blockIdx.y * ROWS_PER_BLOCK;

    // Stage this block's 256 x-rows into padded LDS (4096 slots)
    for (int idx = threadIdx.x; idx < ROWS_PER_BLOCK * XS_STRIDE; idx += TPB) {
        const int row = idx >> 4, col = idx & 15;
        xs[idx] = (col < INPUT_DIM) ? x[(size_t)(row0 + row) * INPUT_DIM + col] : 0.0f;
    }

    // This thread's 4 fixed weight columns in registers.
    f32x4 mw[INPUT_DIM];
#pragma unroll
    for (int i = 0; i < INPUT_DIM; ++i) {
        f32x4 wv = *reinterpret_cast<const f32x4*>(&w[(size_t)i * UNITS + u0]);
        if constexpr (!PREMASKED) {
            wv.x *= mask[(size_t)(u0 + 0) * INPUT_DIM + i];
            wv.y *= mask[(size_t)(u0 + 1) * INPUT_DIM + i];
            wv.z *= mask[(size_t)(u0 + 2) * INPUT_DIM + i];
            wv.w *= mask[(size_t)(u0 + 3) * INPUT_DIM + i];
        }
        mw[i] = wv;
    }
    const f32x4 bv = *reinterpret_cast<const f32x4*>(&bias[u0]);

    __syncthreads();

    const f32x4* xs4 = reinterpret_cast<const f32x4*>(xs);

    // 4 rows in flight: independent FMA chains + 4 outstanding nt stores.
    for (int r = 0; r < ROWS_PER_BLOCK; r += R_UNROLL) {
        float v[R_UNROLL][16];
#pragma unroll
        for (int rr = 0; rr < R_UNROLL; ++rr) {
#pragma unroll
            for (int j = 0; j < 4; ++j) {
                const f32x4 t = xs4[(r + rr) * 4 + j];
                v[rr][j * 4 + 0] = t.x;
                v[rr][j * 4 + 1] = t.y;
                v[rr][j * 4 + 2] = t.z;
                v[rr][j * 4 + 3] = t.w;
            }
        }
        f32x4 acc[R_UNROLL];
#pragma unroll
        for (int rr = 0; rr < R_UNROLL; ++rr) acc[rr] = bv;
#pragma unroll
        for (int i = 0; i < INPUT_DIM; ++i) {
#pragma unroll
            for (int rr = 0; rr < R_UNROLL; ++rr) {
                acc[rr].x = fmaf(v[rr][i], mw[i].x, acc[rr].x);
                acc[rr].y = fmaf(v[rr][i], mw[i].y, acc[rr].y);
                acc[rr].z = fmaf(v[rr][i], mw[i].z, acc[rr].z);
                acc[rr].w = fmaf(v[rr][i], mw[i].w, acc[rr].w);
            }
        }
#pragma unroll
        for (int rr = 0; rr < R_UNROLL; ++rr) {
            __builtin_nontemporal_store(acc[rr],
                reinterpret_cast<f32x4*>(&out[(size_t)(row0 + r + rr) * UNITS + u0]));
        }
    }
}

extern "C" void kernel_launch(void* const* d_in, const int* in_sizes, int n_in,
                              void* d_out, int out_size, void* d_ws, size_t ws_size,
                              hipStream_t stream) {
    const float* x    = (const float*)d_in[0];  // inputs [2048, 15]
    const float* w    = (const float*)d_in[1];  // w      [15, 49152]
    const float* b    = (const float*)d_in[2];  // b      [49152]
    const float* mask = (const float*)d_in[3];  // mask   [49152, 15]
    float* out        = (float*)d_out;          // [2048, 49152]

    dim3 grid(COL_BLOCKS, ROW_GROUPS);  // 32 x 8 = 256 blocks = 1 per CU
    const size_t mw_bytes = (size_t)INPUT_DIM * UNITS * sizeof(float);  // 2.95 MB

    if (ws_size >= mw_bytes) {
        float* mw = (float*)d_ws;
        premask_kernel<<<UNITS / 256, 256, 0, stream>>>(w, mask, mw);
        striatum_kernel<true><<<grid, TPB, 0, stream>>>(x, mw, b, mask, out);
    } else {
        striatum_kernel<false><<<grid, TPB, 0, stream>>>(x, w, b, mask, out);
    }
}